// Round 3
// baseline (137.858 us; speedup 1.0000x reference)
//
#include <hip/hip_runtime.h>

// KspaceFillNeighbourLayer: temporal clipped box-filter sums (radii 0,1,2,4)
// over T=30 frames + masked blend.
// k,mask = (n,2,T,H,W) f32; out = (n,4,2,T,H,W) f32.
//
// One thread per pixel column (n,c,h,w): prefix sum of k over T in registers
// (31 VGPR), mask packed into a 30-bit integer (mask is exactly 0/1).
// Window sums: k via cs[hi]-cs[lo]; mask via popc(bits & static range mask).
// Divide via v_rcp_f32 (rel err ~1e-7 vs 0.2975 threshold); blend is an
// exact bit-select. Nontemporal loads/stores keep the 378 MB stream out of
// L2/L3. __launch_bounds__(256,8) pins VGPR<=64 -> 32 waves/CU; grid = 2048
// blocks = exactly one full wave-generation on 256 CUs.

#define T_FRAMES 30
constexpr int kP = 256 * 256;   // H*W

__global__ __launch_bounds__(256, 8) void kfill_kernel(
    const float* __restrict__ k, const float* __restrict__ mask,
    float* __restrict__ out, int total)
{
    int tid = blockIdx.x * blockDim.x + threadIdx.x;
    if (tid >= total) return;

    int col  = tid >> 16;          // tid / kP
    int pix  = tid & (kP - 1);
    int nidx = col >> 1;
    int c    = col & 1;

    const float* kp = k    + (size_t)col * (T_FRAMES * kP) + pix;
    const float* mp = mask + (size_t)col * (T_FRAMES * kP) + pix;

    // Prefix sum of k (registers) + packed mask bits.
    float cs[T_FRAMES + 1];
    cs[0] = 0.0f;
    unsigned bits = 0;
#pragma unroll
    for (int t = 0; t < T_FRAMES; ++t) {
        float kvt = __builtin_nontemporal_load(kp + (size_t)t * kP);
        float mvt = __builtin_nontemporal_load(mp + (size_t)t * kP);
        cs[t + 1] = cs[t] + kvt;
        bits |= ((unsigned)mvt) << t;   // mvt is exactly 0.0f or 1.0f
    }

    float* outBase = out + (size_t)(nidx * 8 + c) * (T_FRAMES * kP) + pix;
    const int FD[4] = {0, 1, 2, 4};

#pragma unroll
    for (int f = 0; f < 4; ++f) {
        const int d = FD[f];
        float* op = outBase + (size_t)f * (2 * T_FRAMES * kP);
#pragma unroll
        for (int t = 0; t < T_FRAMES; ++t) {
            const int lo = (t - d < 0) ? 0 : t - d;
            const int hi = (t + d + 1 > T_FRAMES) ? T_FRAMES : t + d + 1;
            const unsigned rm = ((1u << hi) - 1) & ~((1u << lo) - 1); // static

            float wk = cs[hi] - cs[lo];
            float wm = (float)__popc(bits & rm);
            float res = wk * __builtin_amdgcn_rcpf(fmaxf(wm, 1.0f));
            float kvt = cs[t + 1] - cs[t];   // exact enough: passed at 0.031
            float o = ((bits >> t) & 1u) ? kvt : res;
            __builtin_nontemporal_store(o, op + (size_t)t * kP);
        }
    }
}

extern "C" void kernel_launch(void* const* d_in, const int* in_sizes, int n_in,
                              void* d_out, int out_size, void* d_ws, size_t ws_size,
                              hipStream_t stream) {
    const float* k    = (const float*)d_in[0];
    const float* mask = (const float*)d_in[1];
    float* out = (float*)d_out;

    const int total = in_sizes[0] / T_FRAMES;   // n*2*H*W columns
    const int block = 256;
    const int grid = (total + block - 1) / block;
    kfill_kernel<<<grid, block, 0, stream>>>(k, mask, out, total);
}

// Round 4
// 84.286 us; speedup vs baseline: 1.6356x; 1.6356x over previous
//
#include <hip/hip_runtime.h>

// KspaceFillNeighbourLayer: temporal clipped box-filter sums (radii 0,1,2,4)
// over T=30 frames + masked blend.
// k,mask = (n,2,T,H,W) f32; out = (n,4,2,T,H,W) f32.
//
// One thread per pixel column (n,c,h,w). Prefix sum of k over T in registers;
// mask packed into a 30-bit integer (mask values are exactly 0/1) so mask
// window sums are popc(bits & static-range-mask) -- saves 31 VGPRs vs a
// second prefix array. Divide via v_rcp_f32 (~1e-7 rel err vs 0.2975
// threshold); blend is an exact bit-select.
// NO forced occupancy cap (R3 lesson: __launch_bounds__(256,8) -> VGPR=32 ->
// ~170 MB of scratch spill traffic, 137 us). Natural allocation ~50 VGPR
// should give 8 waves/SIMD without spilling.
// Memory-bound: 126 MB read + 252 MB write minimum.

#define T_FRAMES 30
constexpr int kP = 256 * 256;   // H*W

__global__ __launch_bounds__(256) void kfill_kernel(
    const float* __restrict__ k, const float* __restrict__ mask,
    float* __restrict__ out, int total)
{
    int tid = blockIdx.x * blockDim.x + threadIdx.x;
    if (tid >= total) return;

    int col  = tid >> 16;          // tid / kP  (P = 2^16)
    int pix  = tid & (kP - 1);
    int nidx = col >> 1;
    int c    = col & 1;

    const float* kp = k    + (size_t)col * (T_FRAMES * kP) + pix;
    const float* mp = mask + (size_t)col * (T_FRAMES * kP) + pix;

    // Prefix sum of k (registers) + packed mask bits.
    float cs[T_FRAMES + 1];
    cs[0] = 0.0f;
    unsigned bits = 0;
#pragma unroll
    for (int t = 0; t < T_FRAMES; ++t) {
        float kvt = kp[(size_t)t * kP];
        float mvt = mp[(size_t)t * kP];
        cs[t + 1] = cs[t] + kvt;
        bits |= ((unsigned)mvt) << t;   // mvt is exactly 0.0f or 1.0f
    }

    float* outBase = out + (size_t)(nidx * 8 + c) * (T_FRAMES * kP) + pix;
    const int FD[4] = {0, 1, 2, 4};

#pragma unroll
    for (int f = 0; f < 4; ++f) {
        const int d = FD[f];
        float* op = outBase + (size_t)f * (2 * T_FRAMES * kP);
#pragma unroll
        for (int t = 0; t < T_FRAMES; ++t) {
            const int lo = (t - d < 0) ? 0 : t - d;
            const int hi = (t + d + 1 > T_FRAMES) ? T_FRAMES : t + d + 1;
            const unsigned rm = ((1u << hi) - 1) & ~((1u << lo) - 1); // static

            float wk = cs[hi] - cs[lo];
            float wm = (float)__popc(bits & rm);
            float res = wk * __builtin_amdgcn_rcpf(fmaxf(wm, 1.0f));
            float kvt = cs[t + 1] - cs[t];   // per-frame k, exact enough
            float o = ((bits >> t) & 1u) ? kvt : res;
            op[(size_t)t * kP] = o;
        }
    }
}

extern "C" void kernel_launch(void* const* d_in, const int* in_sizes, int n_in,
                              void* d_out, int out_size, void* d_ws, size_t ws_size,
                              hipStream_t stream) {
    const float* k    = (const float*)d_in[0];
    const float* mask = (const float*)d_in[1];
    float* out = (float*)d_out;

    const int total = in_sizes[0] / T_FRAMES;   // n*2*H*W columns
    const int block = 256;
    const int grid = (total + block - 1) / block;
    kfill_kernel<<<grid, block, 0, stream>>>(k, mask, out, total);
}

// Round 5
// 61.200 us; speedup vs baseline: 2.2526x; 1.3772x over previous
//
#include <hip/hip_runtime.h>

// KspaceFillNeighbourLayer: temporal clipped box-filter sums (radii 0,1,2,4)
// over T=30 frames + masked blend. k,mask = (n,2,T,H,W) f32; out = (n,4,2,T,H,W) f32.
//
// One thread per pixel column. SOFTWARE-PIPELINED BY READINESS: as frame s is
// loaded, immediately store every output whose window just completed --
//   f=0 (d=0): out0[s] == k[s] exactly (res = k/clip(m,1) = k for m in {0,1})
//   f=1 (d=1): out1[s-1];  f=2 (d=2): out2[s-2];  f=3 (d=4): out3[s-4]
// Steady state = 2 loads + 4 stores per step -> read & write HBM streams stay
// concurrently active (R1-R4 all did 60 loads THEN 120 stores; lockstep waves
// made the device alternate read-phase/write-phase, capping at ~4.7 TB/s).
// sched_barrier(0) per iteration pins the interleave (compiler otherwise
// re-hoists all loads). Mask packed into 30 bits -> popc window sums; rcp
// divide (~1e-7 rel err vs 0.2975 threshold); nontemporal stores (output is
// never re-read; avoids any write-allocate fetch).

#define T_FRAMES 30
constexpr int kP = 256 * 256;   // H*W

__global__ __launch_bounds__(256) void kfill_kernel(
    const float* __restrict__ k, const float* __restrict__ mask,
    float* __restrict__ out, int total)
{
    int tid = blockIdx.x * blockDim.x + threadIdx.x;
    if (tid >= total) return;

    int col  = tid >> 16;          // tid / kP  (kP = 2^16)
    int pix  = tid & (kP - 1);
    int nidx = col >> 1;
    int c    = col & 1;

    const float* kp = k    + (size_t)col * (T_FRAMES * kP) + pix;
    const float* mp = mask + (size_t)col * (T_FRAMES * kP) + pix;

    float* outBase = out + (size_t)(nidx * 8 + c) * (T_FRAMES * kP) + pix;
    float* op0 = outBase;                                  // f=0, d=0
    float* op1 = outBase + (size_t)(2 * T_FRAMES * kP);    // f=1, d=1
    float* op2 = outBase + (size_t)(4 * T_FRAMES * kP);    // f=2, d=2
    float* op3 = outBase + (size_t)(6 * T_FRAMES * kP);    // f=3, d=4

    float cs[T_FRAMES + 1];       // only a ~9-entry sliding window stays live
    cs[0] = 0.0f;
    unsigned bits = 0;

    auto emit = [&](float* op, int t, int d) {
        const int lo = (t - d < 0) ? 0 : t - d;
        const int hi = (t + d + 1 > T_FRAMES) ? T_FRAMES : t + d + 1;
        const unsigned rm = ((1u << hi) - 1) & ~((1u << lo) - 1); // static
        float wk = cs[hi] - cs[lo];
        float wm = (float)__popc(bits & rm);
        float res = wk * __builtin_amdgcn_rcpf(fmaxf(wm, 1.0f));
        float kvt = cs[t + 1] - cs[t];
        float o = ((bits >> t) & 1u) ? kvt : res;
        __builtin_nontemporal_store(o, op + (size_t)t * kP);
    };

#pragma unroll
    for (int s = 0; s < T_FRAMES; ++s) {
        float kvt = kp[(size_t)s * kP];
        float mvt = mp[(size_t)s * kP];
        cs[s + 1] = cs[s] + kvt;
        bits |= ((unsigned)mvt) << s;      // mvt is exactly 0.0f or 1.0f

        __builtin_nontemporal_store(kvt, op0 + (size_t)s * kP);  // f=0 == k
        if (s >= 1) emit(op1, s - 1, 1);
        if (s >= 2) emit(op2, s - 2, 2);
        if (s >= 4) emit(op3, s - 4, 4);
        __builtin_amdgcn_sched_barrier(0); // keep the load/store interleave
    }

    // clipped tails (windows that end at T)
    emit(op1, 29, 1);
    emit(op2, 28, 2); emit(op2, 29, 2);
    emit(op3, 26, 4); emit(op3, 27, 4); emit(op3, 28, 4); emit(op3, 29, 4);
}

extern "C" void kernel_launch(void* const* d_in, const int* in_sizes, int n_in,
                              void* d_out, int out_size, void* d_ws, size_t ws_size,
                              hipStream_t stream) {
    const float* k    = (const float*)d_in[0];
    const float* mask = (const float*)d_in[1];
    float* out = (float*)d_out;

    const int total = in_sizes[0] / T_FRAMES;   // n*2*H*W columns = 524288
    const int block = 256;
    const int grid = (total + block - 1) / block;
    kfill_kernel<<<grid, block, 0, stream>>>(k, mask, out, total);
}